// Round 3
// baseline (74.406 us; speedup 1.0000x reference)
//
#include <hip/hip_runtime.h>
#include <stdint.h>
#include <math.h>

// ---------------------------------------------------------------------------
// SparseExplorerRouting, round 6.
//
// Carried facts (R1-R3, R5 PASSED, absmax 0; R4 regressed, reverted):
//   * jax_threefry_partitionable=True counter scheme; key(42) -> (0,42);
//     walk (v,w) = split child v*5+w; per-step children ctr (0,{0,1,2}).
//   * output int32 {flags[1024], sum_aborts, sum_restarts}.
//   * f64 analog math proxy for the f32 reference passes with margin.
//   * E-table argmax(E/w) trick, w=-log(u); minE<e^0.5 == min_sim<0.1.
//   * R4 lesson: walk is latency/issue bound; don't perturb the schedule
//     with micro-reorderings. R5 lesson: runtime-indexed locals spill.
//   * R5 walk = 42us, VALUBusy 70%, HBM 1.3% -> VALU-issue bound with only
//     32/64 productive lanes in the hot branch (j=16 excluded => exactly 32
//     valid candidates).
//
// Round 6 change (walk only; band kept from R5):
//   * TWO WALKS PER WAVE: lanes 0..31 = walk A, lanes 32..63 = walk B;
//     lane l handles candidate j = l + (l>=16), skipping j=16 (== cur,
//     which can never win: logit -5e9). All 64 lanes productive in the
//     expensive threefry/log/div branch; butterfly drops 6->5 stages.
//     Both halves' key chains stay SALU; per-lane 2-op select feeds the
//     per-lane fold. break -> per-half act masking (reference semantics).
//     All produced values bit-identical to R5; only lane mapping changed.
// ---------------------------------------------------------------------------

#define HID        1024
#define NUM_WALKS  5
#define WALK_LEN   8
#define HALF_WIN   16
#define E_THRESH   1.6487212707001282   // exp(0.5) = exp(5 * BIRTH_DEATH_EPS)

#define CENTERS    16                   // centers per band block
#define SROWS      32                   // staged rows = CENTERS + 16 halo

__device__ __forceinline__ void tf2x32(uint32_t k0, uint32_t k1,
                                       uint32_t& x0, uint32_t& x1) {
  uint32_t ks2 = k0 ^ k1 ^ 0x1BD11BDAu;
  x0 += k0; x1 += k1;
#define TFR(r) { x0 += x1; x1 = (x1 << (r)) | (x1 >> (32 - (r))); x1 ^= x0; }
  TFR(13) TFR(15) TFR(26) TFR(6)
  x0 += k1;  x1 += ks2 + 1u;
  TFR(17) TFR(29) TFR(16) TFR(24)
  x0 += ks2; x1 += k0 + 2u;
  TFR(13) TFR(15) TFR(26) TFR(6)
  x0 += k0;  x1 += k1 + 3u;
  TFR(17) TFR(29) TFR(16) TFR(24)
  x0 += k1;  x1 += ks2 + 4u;
  TFR(13) TFR(15) TFR(26) TFR(6)
  x0 += ks2; x1 += k0 + 5u;
#undef TFR
}

__device__ __forceinline__ uint32_t tf_fold(uint32_t k0, uint32_t k1,
                                            uint32_t c0, uint32_t c1) {
  tf2x32(k0, k1, c0, c1);
  return c0 ^ c1;
}

// ---- fused band + rowsq + d_out zeroing (unchanged from R5) ----------------
__global__ __launch_bounds__(512) void band_fused_kernel(
    const float* __restrict__ H, double* __restrict__ sumsq,
    double* __restrict__ E, int* __restrict__ out, int out_n, int seq_len) {
  __shared__ __align__(16) float  tile[SROWS][HID];   // 128 KB
  __shared__ double ssq[SROWS];

  if (blockIdx.x == 0) {                 // fold d_out zeroing in (dispatch
    for (int t = threadIdx.x; t < out_n; t += 512) out[t] = 0;   // ordering
  }                                      // guarantees walk sees zeros)

  int wg = blockIdx.x;
  {
    const int nwg = gridDim.x;           // bijective XCD swizzle (nwg%8==0)
    if ((nwg & 7) == 0) wg = (wg & 7) * (nwg >> 3) + (wg >> 3);
  }
  const int wid  = (int)(threadIdx.x >> 6);   // 0..7
  const int lane = (int)(threadIdx.x & 63);
  const int i0   = wg * CENTERS;
  const float4* __restrict__ H4 = (const float4*)H;

  // ---- stage 4 rows per wave + sumsq (same order as old rowsq) ----
#pragma unroll
  for (int rr = 0; rr < 4; ++rr) {
    const int local = wid * 4 + rr;      // wave-uniform
    const int row   = i0 + local;
    if (row < seq_len) {
      const float4* src = H4 + ((size_t)row << 8);
      float4* dst = (float4*)&tile[local][0];
      double acc = 0.0;
#pragma unroll
      for (int k = 0; k < 4; ++k) {
        float4 x = src[lane + (k << 6)];
        dst[lane + (k << 6)] = x;
        acc += (double)x.x * x.x + (double)x.y * x.y
             + (double)x.z * x.z + (double)x.w * x.w;
      }
#pragma unroll
      for (int off = 32; off; off >>= 1) acc += __shfl_xor(acc, off);
      if (lane == 0) {
        ssq[local] = acc;
        if (local < CENTERS) sumsq[row] = acc;   // each row owned by 1 block
      }
    }
  }
  __syncthreads();

  // ---- 2 centers per wave, 16 forward dots each, from LDS ----
#pragma unroll
  for (int cc = 0; cc < 2; ++cc) {
    const int cl = wid * 2 + cc;         // 0..15, wave-uniform
    const int i  = i0 + cl;
    if (i >= seq_len) continue;

    double a[16];
    {
      const float4* rc = (const float4*)&tile[cl][0];
#pragma unroll
      for (int k = 0; k < 4; ++k) {
        float4 x = rc[lane + (k << 6)];
        a[4*k+0] = x.x; a[4*k+1] = x.y; a[4*k+2] = x.z; a[4*k+3] = x.w;
      }
    }
    const double ni = sqrt(ssq[cl]) + 1e-8;

    // d-loop fully unrolled: p[] indices static -> registers, no scratch.
    // Halo-row garbage partials (i+d >= seq_len) stay segregated per-d and
    // never reach the guarded write. Bit-identical valid E.
    double p[16];
#pragma unroll
    for (int d = 0; d < 16; ++d) p[d] = 0.0;
#pragma unroll
    for (int d = 1; d <= 16; ++d) {
      const float4* rb = (const float4*)&tile[cl + d][0];
#pragma unroll
      for (int k = 0; k < 4; ++k) {
        float4 x = rb[lane + (k << 6)];
        p[d-1] += a[4*k+0] * (double)x.x + a[4*k+1] * (double)x.y
                + a[4*k+2] * (double)x.z + a[4*k+3] * (double)x.w;
      }
    }

    // multi-value reduce-scatter: value bit3..0 <- lane bit5..2
#pragma unroll
    for (int v = 0; v < 8; ++v) {                     // stage xor 32
      double send = (lane & 32) ? p[v] : p[v+8];
      double recv = __shfl_xor(send, 32);
      double mine = (lane & 32) ? p[v+8] : p[v];
      p[v] = mine + recv;
    }
#pragma unroll
    for (int v = 0; v < 4; ++v) {                     // stage xor 16
      double send = (lane & 16) ? p[v] : p[v+4];
      double recv = __shfl_xor(send, 16);
      double mine = (lane & 16) ? p[v+4] : p[v];
      p[v] = mine + recv;
    }
#pragma unroll
    for (int v = 0; v < 2; ++v) {                     // stage xor 8
      double send = (lane & 8) ? p[v] : p[v+2];
      double recv = __shfl_xor(send, 8);
      double mine = (lane & 8) ? p[v+2] : p[v];
      p[v] = mine + recv;
    }
    {                                                 // stage xor 4
      double send = (lane & 4) ? p[0] : p[1];
      double recv = __shfl_xor(send, 4);
      double mine = (lane & 4) ? p[1] : p[0];
      p[0] = mine + recv;
    }
    p[0] += __shfl_xor(p[0], 2);                      // stage xor 2
    p[0] += __shfl_xor(p[0], 1);                      // stage xor 1

    const int v = ((lane >> 2) & 1) | (((lane >> 3) & 1) << 1)
                | (((lane >> 4) & 1) << 2) | (((lane >> 5) & 1) << 3);
    const int d = v + 1;
    if ((lane & 3) == 0 && i + d < seq_len) {
      const double s  = p[0] / (ni * (sqrt(ssq[cl + d]) + 1e-8));
      const double Ev = exp(5.0 * s);
      E[(size_t)i * 33 + 16 + d]       = Ev;
      E[(size_t)(i + d) * 33 + 16 - d] = Ev;
    }
  }
}

// ---- per-row sum of squares (f64) + d_out zeroing (FALLBACK path only) -----
__global__ __launch_bounds__(256) void rowsq_kernel(
    const float* __restrict__ H, double* __restrict__ sumsq,
    int* __restrict__ out, int out_n, int seq_len) {
  if (blockIdx.x == 0) {
    for (int t = threadIdx.x; t < out_n; t += 256) out[t] = 0;
  }
  const int row  = (int)((blockIdx.x * blockDim.x + threadIdx.x) >> 6);
  const int lane = threadIdx.x & 63;
  if (row >= seq_len) return;
  const float4* r = (const float4*)(H + (size_t)row * HID);
  double acc = 0.0;
#pragma unroll
  for (int k = 0; k < 4; ++k) {
    float4 x = r[lane + (k << 6)];
    acc += (double)x.x * x.x + (double)x.y * x.y
         + (double)x.z * x.z + (double)x.w * x.w;
  }
#pragma unroll
  for (int off = 32; off; off >>= 1) acc += __shfl_xor(acc, off);
  if (lane == 0) sumsq[row] = acc;
}

// ---- walk kernel: TWO walks per wave (32 lanes each) -----------------------
// Valid candidates are j in {0..32}\{16} == 32 positions; lane l in a half
// handles j = l + (l>=16). All values bit-identical to the 1-walk version.
__global__ __launch_bounds__(256) void walk_pair_kernel(
    const double* __restrict__ E, const double* __restrict__ sumsq,
    const int* __restrict__ viol, int* __restrict__ out,
    int nv, int seq_len) {
  const int nwalks = nv * NUM_WALKS;
  int W = (int)((blockIdx.x * blockDim.x + threadIdx.x) >> 6);  // wave-pair id
  const int lane = threadIdx.x & 63;
  if (W * 2 >= nwalks) return;
  W = __builtin_amdgcn_readfirstlane(W);

  const int  half = lane >> 5;              // 0 = walk A, 1 = walk B
  const int  l    = lane & 31;
  const int  j    = l + (l >> 4);           // skip j=16 (cur; can't win)
  const int  wA   = W * 2, wB = W * 2 + 1;  // global walk ids
  const bool hasB = (wB < nwalks);

  // scalar (SALU) key chains for both halves
  uint32_t kA0 = 0u, kA1 = (uint32_t)wA; tf2x32(0u, 42u, kA0, kA1);
  uint32_t kB0 = 0u, kB1 = (uint32_t)wB; tf2x32(0u, 42u, kB0, kB1);
  kA0 = __builtin_amdgcn_readfirstlane(kA0);
  kA1 = __builtin_amdgcn_readfirstlane(kA1);
  kB0 = __builtin_amdgcn_readfirstlane(kB0);
  kB1 = __builtin_amdgcn_readfirstlane(kB1);

  const int myw   = (half && hasB) ? wB : wA;
  const int myv   = myw / NUM_WALKS;
  const int start = viol[myv];

  int    cur = start, prev = start, plen = 1;
  double minE = 1e300;
  bool   detected = false;
  int    aborts = 0, restarts = 0;
  bool   act  = half ? hasB : true;
  double na_d = sumsq[start], nb_d = na_d;

  for (int step = 0; step < WALK_LEN; ++step) {
    if (__all(!act)) break;               // both walks finished

    // split(key,3) for both halves -- SALU
    uint32_t nkA0 = 0u, nkA1 = 0u; tf2x32(kA0, kA1, nkA0, nkA1);
    uint32_t ksA0 = 0u, ksA1 = 1u; tf2x32(kA0, kA1, ksA0, ksA1);
    uint32_t krA0 = 0u, krA1 = 2u; tf2x32(kA0, kA1, krA0, krA1);
    uint32_t nkB0 = 0u, nkB1 = 0u; tf2x32(kB0, kB1, nkB0, nkB1);
    uint32_t ksB0 = 0u, ksB1 = 1u; tf2x32(kB0, kB1, ksB0, ksB1);
    uint32_t krB0 = 0u, krB1 = 2u; tf2x32(kB0, kB1, krB0, krB1);

    const int  myidx = cur - HALF_WIN + j;
    const bool inwin = (myidx >= 0) && (myidx < seq_len);
    const int  clip  = myidx < 0 ? 0 : (myidx >= seq_len ? seq_len - 1 : myidx);
    const double Ej     = E[(size_t)cur * 33 + j];
    const double sq_win = sumsq[clip];    // == sumsq[myidx] where valid

    bool found = false; int fails = 0, p = 0, cand = 0;
    double nc_d = 0.0;
    for (int at = 0; at < 3; ++at) {
      uint32_t sA0 = 0u, sA1 = (uint32_t)at; tf2x32(ksA0, ksA1, sA0, sA1);
      uint32_t sB0 = 0u, sB1 = (uint32_t)at; tf2x32(ksB0, ksB1, sB0, sB1);
      const uint32_t s0 = half ? sB0 : sA0;   // 2-op per-lane select
      const uint32_t s1 = half ? sB1 : sA1;

      double f; int bi;
      if (act && !found && inwin) {       // half-uniform act/found
        const uint32_t bits = tf_fold(s0, s1, 0u, (uint32_t)j);
        const uint32_t fb   = (bits >> 9) | 0x3f800000u;
        const float    ff   = __uint_as_float(fb) - 1.0f;
        const float    u    = (ff > 0.0f) ? ff : 1.1754943508222875e-38f;
        const double   w    = -log((double)u);        // w > 0
        f  = Ej / w;          // argmax(E/w) == argmax(5*sim + gumbel)
        bi = j;
      } else { f = -1.0; bi = 1000; }
      // 5-stage butterfly within each 32-lane half (xor<32 stays in half)
#pragma unroll
      for (int off = 16; off; off >>= 1) {
        const double of = __shfl_xor(f, off);
        const int    oi = __shfl_xor(bi, off);
        if (of > f || (of == f && oi < bi)) { f = of; bi = oi; }
      }
      if (act && !found) {
        p    = bi;
        cand = cur - HALF_WIN + p;
        const int srcl = (half << 5) + (p > HALF_WIN ? p - 1 : p);
        nc_d = __shfl(sq_win, srcl);      // == sumsq[cand]; src in own half
        bool ok;
        if (plen < 2) ok = true;
        else {
          const float na = (float)na_d, nb = (float)nb_d, nc = (float)nc_d;
          const float tr  = (na * nb * nc) /
                            ((na + 1e-8f) * (nb + 1e-8f) * (nc + 1e-8f));
          const float dev = fabsf(tr - rintf(tr));
          ok = (dev <= 0.1f) && (tr <= 1.5f);
        }
        if (ok) found = true; else ++fails;
      }
      if (__all(found || !act)) break;
    }
    aborts += fails;                      // fails gated by act above

    // winning E value (source lane inside own half; garbage if unused)
    const int srcw = (half << 5) + ((p > HALF_WIN ? p - 1 : p) & 31);
    const double Ewin = __shfl(Ej, srcw);

    const bool nf = act && !found;
    if (act && found) {
      minE = fmin(minE, Ewin);
      const bool closed = (cand == start) && (plen > 2);
      prev = cur; cur = cand; plen += 1;
      na_d = nb_d; nb_d = nc_d;
      if (closed) { if (minE < E_THRESH) detected = true; act = false; }
    }
    int rA = 0, rB = 0;
    if (__any(nf)) {                      // rare path: restart indices, SALU
      uint32_t hA0 = 0u, hA1 = 0u; tf2x32(krA0, krA1, hA0, hA1);
      uint32_t lA0 = 0u, lA1 = 1u; tf2x32(krA0, krA1, lA0, lA1);
      uint32_t hB0 = 0u, hB1 = 0u; tf2x32(krB0, krB1, hB0, hB1);
      uint32_t lB0 = 0u, lB1 = 1u; tf2x32(krB0, krB1, lB0, lB1);
      const uint32_t hiA = tf_fold(hA0, hA1, 0u, 0u);
      const uint32_t loA = tf_fold(lA0, lA1, 0u, 0u);
      const uint32_t hiB = tf_fold(hB0, hB1, 0u, 0u);
      const uint32_t loB = tf_fold(lB0, lB1, 0u, 0u);
      const uint32_t span = (uint32_t)nv;
      uint32_t mult = (65536u % span); mult = (mult * mult) % span;
      rA = (int)(((hiA % span) * mult + (loA % span)) % span);
      rB = (int)(((hiB % span) * mult + (loB % span)) % span);
    }
    if (nf) {
      ++restarts;
      const int r    = half ? rB : rA;
      const int node = viol[r];
      cur = node; prev = node; plen = 1;
      na_d = sumsq[node]; nb_d = na_d;
    }

    kA0 = __builtin_amdgcn_readfirstlane(nkA0);
    kA1 = __builtin_amdgcn_readfirstlane(nkA1);
    kB0 = __builtin_amdgcn_readfirstlane(nkB0);
    kB1 = __builtin_amdgcn_readfirstlane(nkB1);
  }

  if ((lane & 31) == 0 && (half == 0 || hasB)) {
    if (detected)      atomicOr(&out[myv], 1);
    if (aborts != 0)   atomicAdd(&out[nv], aborts);
    if (restarts != 0) atomicAdd(&out[nv + 1], restarts);
  }
}

// ---- fallback: round-1 in-walk dot kernel (only if ws too small) -----------
__global__ __launch_bounds__(256) void walk_ref_kernel(
    const float* __restrict__ H, const int* __restrict__ viol,
    const double* __restrict__ sumsq, int* __restrict__ out,
    int nv, int seq_len) {
  const int wave = (int)((blockIdx.x * blockDim.x + threadIdx.x) >> 6);
  const int lane = threadIdx.x & 63;
  if (wave >= nv * NUM_WALKS) return;
  const int v     = wave / NUM_WALKS;
  const int start = viol[v];
  uint32_t key0 = 0u, key1 = (uint32_t)wave;
  tf2x32(0u, 42u, key0, key1);
  const float4* __restrict__ H4 = (const float4*)H;
  int    cur = start, prev = start, plen = 1;
  double min_sim = 1e9;
  bool   detected = false;
  int    aborts = 0, restarts = 0;
  for (int step = 0; step < WALK_LEN; ++step) {
    uint32_t nk0 = 0u, nk1 = 0u; tf2x32(key0, key1, nk0, nk1);
    uint32_t ks0 = 0u, ks1 = 1u; tf2x32(key0, key1, ks0, ks1);
    uint32_t kr0 = 0u, kr1 = 2u; tf2x32(key0, key1, kr0, kr1);
    const double ncur = sqrt(sumsq[cur]) + 1e-8;
    double a[16];
    {
      const float4* rc = H4 + ((size_t)cur << 8);
#pragma unroll
      for (int k = 0; k < 4; ++k) {
        float4 x = rc[lane + (k << 6)];
        a[4*k+0] = x.x; a[4*k+1] = x.y; a[4*k+2] = x.z; a[4*k+3] = x.w;
      }
    }
    double my_sim = 0.0;
    for (int jj = 0; jj < 33; ++jj) {
      const int idx = cur - HALF_WIN + jj;
      if (jj == HALF_WIN || idx < 0 || idx >= seq_len) continue;
      const float4* rb = H4 + ((size_t)idx << 8);
      double acc = 0.0;
#pragma unroll
      for (int k = 0; k < 4; ++k) {
        float4 x = rb[lane + (k << 6)];
        acc += a[4*k+0] * (double)x.x + a[4*k+1] * (double)x.y
             + a[4*k+2] * (double)x.z + a[4*k+3] * (double)x.w;
      }
#pragma unroll
      for (int off = 32; off; off >>= 1) acc += __shfl_xor(acc, off);
      const double s = acc / (ncur * (sqrt(sumsq[idx]) + 1e-8));
      if (lane == jj) my_sim = s;
    }
    bool found = false; int fails = 0, p = 0, cand = 0;
    const int  myidx   = cur - HALF_WIN + lane;
    const bool myvalid = (lane < 33) && (lane != HALF_WIN) &&
                         (myidx >= 0) && (myidx < seq_len);
    for (int at = 0; at < 3; ++at) {
      uint32_t s0 = 0u, s1 = (uint32_t)at; tf2x32(ks0, ks1, s0, s1);
      double z; int bi;
      if (myvalid) {
        const uint32_t bits = tf_fold(s0, s1, 0u, (uint32_t)lane);
        const uint32_t fb   = (bits >> 9) | 0x3f800000u;
        const float    f    = __uint_as_float(fb) - 1.0f;
        const float    u    = (f > 0.0f) ? f : 1.1754943508222875e-38f;
        const double   g    = -log(-log((double)u));
        z  = g + 5.0 * my_sim;
        bi = lane;
      } else { z = -1e300; bi = 1000; }
#pragma unroll
      for (int off = 32; off; off >>= 1) {
        const double oz = __shfl_xor(z, off);
        const int    oi = __shfl_xor(bi, off);
        if (oz > z || (oz == z && oi < bi)) { z = oz; bi = oi; }
      }
      p    = bi;
      cand = cur - HALF_WIN + p;
      bool ok;
      if (plen < 2) ok = true;
      else {
        const float na = (float)sumsq[prev], nb = (float)sumsq[cur],
                    nc = (float)sumsq[cand];
        const float tr  = (na * nb * nc) /
                          ((na + 1e-8f) * (nb + 1e-8f) * (nc + 1e-8f));
        const float dev = fabsf(tr - rintf(tr));
        ok = (dev <= 0.1f) && (tr <= 1.5f);
      }
      if (ok) { found = true; break; }
      ++fails;
    }
    aborts += fails;
    if (found) {
      const double sim = __shfl(my_sim, p);
      const double nm  = fmin(min_sim, sim);
      const bool closed = (cand == start) && (plen > 2);
      prev = cur; cur = cand; plen += 1; min_sim = nm;
      if (closed) { if (nm < 0.1) detected = true; break; }
    } else {
      ++restarts;
      uint32_t h0 = 0u, h1 = 0u; tf2x32(kr0, kr1, h0, h1);
      uint32_t l0 = 0u, l1 = 1u; tf2x32(kr0, kr1, l0, l1);
      const uint32_t hi = tf_fold(h0, h1, 0u, 0u);
      const uint32_t lo = tf_fold(l0, l1, 0u, 0u);
      const uint32_t span = (uint32_t)nv;
      uint32_t mult = (65536u % span); mult = (mult * mult) % span;
      const uint32_t r = ((hi % span) * mult + (lo % span)) % span;
      const int node = viol[r];
      cur = node; prev = node; plen = 1;
    }
    key0 = nk0; key1 = nk1;
  }
  if (lane == 0) {
    if (detected)      atomicOr(&out[v], 1);
    if (aborts != 0)   atomicAdd(&out[nv], aborts);
    if (restarts != 0) atomicAdd(&out[nv + 1], restarts);
  }
}

extern "C" void kernel_launch(void* const* d_in, const int* in_sizes, int n_in,
                              void* d_out, int out_size, void* d_ws, size_t ws_size,
                              hipStream_t stream) {
  const float* H    = (const float*)d_in[0];
  const int*   viol = (const int*)d_in[1];
  const int    nv      = in_sizes[1];
  const int    seq_len = in_sizes[0] / HID;

  double* sumsq = (double*)d_ws;                       // seq_len * 8 B
  double* Etab  = (double*)((char*)d_ws + (size_t)seq_len * sizeof(double));
  const size_t need = (size_t)seq_len * sizeof(double)
                    + (size_t)seq_len * 33 * sizeof(double);

  const int nwalks = nv * NUM_WALKS;

  if (ws_size >= need) {
    const int blocks = (seq_len + CENTERS - 1) / CENTERS;   // 512 @ 8192
    band_fused_kernel<<<blocks, 512, 0, stream>>>(H, sumsq, Etab,
                                                  (int*)d_out, out_size,
                                                  seq_len);
    const int npairs  = (nwalks + 1) / 2;                   // 2 walks / wave
    const int pblocks = (npairs + 3) / 4;                   // 4 waves / block
    walk_pair_kernel<<<pblocks, 256, 0, stream>>>(Etab, sumsq, viol,
                                                  (int*)d_out, nv, seq_len);
  } else {
    const int blocks  = (seq_len + 3) / 4;
    const int wblocks = (nwalks + 3) / 4;
    rowsq_kernel<<<blocks, 256, 0, stream>>>(H, sumsq, (int*)d_out,
                                             out_size, seq_len);
    walk_ref_kernel<<<wblocks, 256, 0, stream>>>(H, viol, sumsq,
                                                 (int*)d_out, nv, seq_len);
  }
}